// Round 18
// baseline (1241.437 us; speedup 1.0000x reference)
//
#include <hip/hip_runtime.h>
#include <math.h>

// GAT layer, R18: agg stored as bf16 (written once/read twice; BN normalizes
// so bf16 error ~0.4% rel) — saves ~30MB of stream traffic across gather/
// bnstats/final. Pipeline: init -> gemm(+XCD-local edge pass) -> gather ->
// bnstats -> final.

constexpr float NEG_SLOPE = 0.2f;
constexpr float BN_EPS = 1e-5f;
constexpr float SM_EPS = 1e-16f;
constexpr int SLOTS = 96;   // fixed CSR stride per node; P(deg>=96)~1e-44

typedef __attribute__((ext_vector_type(8))) short short8;   // 8 bf16
typedef __attribute__((ext_vector_type(4))) float f32x4;    // MFMA acc

__device__ inline unsigned bf16rne(float f) {
    unsigned b = __float_as_uint(f);
    return (b + 0x7fffu + ((b >> 16) & 1u)) >> 16;
}

// ---------------------------------------------------------------------------
// K0: blocks 0..63: Wt transpose (bf16). blocks 64..71: WS/WD fused attention
// columns (a_s = x @ (W@att_src)). blocks 72..: zero stats+deg.
// ---------------------------------------------------------------------------
__global__ __launch_bounds__(256) void k_init(
    const float* __restrict__ W, const float* __restrict__ att_src,
    const float* __restrict__ att_dst, unsigned short* __restrict__ Wtg,
    int* __restrict__ zbase, int zcount)
{
    int b = blockIdx.x;
    if (b < 64) {
        int idx = b * 256 + threadIdx.x;   // 16384 total
        int k = idx >> 7, nc = idx & 127;
        Wtg[nc * 128 + k] = (unsigned short)bf16rne(W[idx]);
    } else if (b < 72) {
        int c = (b - 64) * 16 + (threadIdx.x >> 4);
        int j = threadIdx.x & 15;
        int h = j & 7;
        const float* att = (j < 8) ? att_src : att_dst;
        float v = 0.f;
#pragma unroll
        for (int f = 0; f < 16; ++f)
            v += W[c * 128 + h * 16 + f] * att[h * 16 + f];
        Wtg[(128 + j) * 128 + c] = (unsigned short)bf16rne(v);
    } else {
        int idx = (b - 72) * 256 + threadIdx.x;
        if (idx < zcount) zbase[idx] = 0;
    }
}

// ---------------------------------------------------------------------------
// K1: XCD-partitioned edge bucketing (cohort = blockIdx%8 owns dst range)
// + MFMA tiles (blocks < ntiles). ct 0..7 -> xp; ct 8 -> [a_s|a_d].
// ---------------------------------------------------------------------------
__global__ __launch_bounds__(256) void k_gemm(
    const float* __restrict__ x, const unsigned short* __restrict__ Wtg,
    const int* __restrict__ ei, int E,
    unsigned* __restrict__ xpb, float* __restrict__ a_s, float* __restrict__ a_d,
    int* __restrict__ deg, unsigned short* __restrict__ csr_src, int n)
{
    // edge pass: cohort (blockIdx%8) scans all edges, keeps dst in its range
    {
        const int xcd = blockIdx.x & 7;
        const int crank = blockIdx.x >> 3;           // rank within cohort
        const int cblocks = gridDim.x >> 3;          // blocks per cohort
        const int nodes_per = (n + 7) >> 3;
        const int dlo = xcd * nodes_per;
        const int dhi = min(n, dlo + nodes_per);
        const int tot = E + n;
        const int stride = cblocks * 256;
        for (int e = crank * 256 + threadIdx.x; e < tot; e += stride) {
            int dst = (e < E) ? ei[E + e] : (e - E);
            if (dst < dlo || dst >= dhi) continue;
            int src = (e < E) ? ei[e] : dst;
            int slot = atomicAdd(&deg[dst], 1);
            csr_src[(size_t)dst * SLOTS + slot] = (unsigned short)src;
        }
    }

    const int ntiles = (n + 63) >> 6;
    if ((int)blockIdx.x >= ntiles) return;

    const int tid = threadIdx.x;
    const int lane = tid & 63;
    const int wid = tid >> 6;
    const int quad = lane >> 4;
    const int l16 = lane & 15;
    const int row = blockIdx.x * 64 + wid * 16 + l16;

    const float4* x4 = (const float4*)x;
    short8 afrag[4];
#pragma unroll
    for (int kt = 0; kt < 4; ++kt) {
        float4 f0 = make_float4(0.f, 0.f, 0.f, 0.f), f1 = f0;
        if (row < n) {
            f0 = x4[(size_t)row * 32 + kt * 8 + quad * 2];
            f1 = x4[(size_t)row * 32 + kt * 8 + quad * 2 + 1];
        }
        short8 a;
        a[0] = (short)bf16rne(f0.x); a[1] = (short)bf16rne(f0.y);
        a[2] = (short)bf16rne(f0.z); a[3] = (short)bf16rne(f0.w);
        a[4] = (short)bf16rne(f1.x); a[5] = (short)bf16rne(f1.y);
        a[6] = (short)bf16rne(f1.z); a[7] = (short)bf16rne(f1.w);
        afrag[kt] = a;
    }

    f32x4 acc[9];
#pragma unroll
    for (int ct = 0; ct < 9; ++ct) acc[ct] = (f32x4){0.f, 0.f, 0.f, 0.f};

#pragma unroll
    for (int ct = 0; ct < 9; ++ct) {
#pragma unroll
        for (int kt = 0; kt < 4; ++kt) {
            short8 b = *(const short8*)&Wtg[(size_t)(ct * 16 + l16) * 128 + kt * 32 + quad * 8];
            acc[ct] = __builtin_amdgcn_mfma_f32_16x16x32_bf16(afrag[kt], b, acc[ct], 0, 0, 0);
        }
    }

    const int rowbase = blockIdx.x * 64 + wid * 16 + quad * 4;
#pragma unroll
    for (int ct = 0; ct < 8; ++ct) {
#pragma unroll
        for (int r = 0; r < 4; ++r) {
            float val = acc[ct][r];
            float other = __shfl_xor(val, 1);
            int orow = rowbase + r;
            if (!(lane & 1) && orow < n) {
                unsigned u = bf16rne(val) | (bf16rne(other) << 16);
                xpb[(size_t)orow * 64 + ct * 8 + (l16 >> 1)] = u;
            }
        }
    }
#pragma unroll
    for (int r = 0; r < 4; ++r) {
        int orow = rowbase + r;
        if (orow < n) {
            float val = acc[8][r];
            if (l16 < 8) a_s[(size_t)orow * 8 + l16] = val;
            else         a_d[(size_t)orow * 8 + (l16 - 8)] = val;
        }
    }
}

// ---------------------------------------------------------------------------
// K2: per-dst gather-aggregate, bf16 messages. ALL batches 8-wide (clamped
// index + zero-weighted lanes; cnt>=1 via self-loop). agg written as bf16x2.
// One wave per node, 4 nodes/block, barrier-free.
// ---------------------------------------------------------------------------
__global__ __launch_bounds__(256) void k_gather(
    const int* __restrict__ deg, const unsigned short* __restrict__ csr_src,
    const float* __restrict__ a_s, const float* __restrict__ a_d,
    const unsigned* __restrict__ xpb, unsigned* __restrict__ aggb, int n)
{
    int node = blockIdx.x * 4 + (threadIdx.x >> 6);
    if (node >= n) return;
    int lane = threadIdx.x & 63;
    int h = lane >> 3;
    float ad = a_d[(size_t)node * 8 + h];
    const unsigned short* rowp = csr_src + (size_t)node * SLOTS;
    int cnt = deg[node];
    float acc0 = 0.f, acc1 = 0.f, s = 0.f;

    for (int slot = 0; slot < cnt; slot += 8) {
        int sx[8]; float w[8]; unsigned u[8];
#pragma unroll
        for (int j = 0; j < 8; ++j) {
            int sj = slot + j;
            sx[j] = rowp[sj < cnt ? sj : cnt - 1];
        }
#pragma unroll
        for (int j = 0; j < 8; ++j) w[j] = a_s[(size_t)sx[j] * 8 + h];
#pragma unroll
        for (int j = 0; j < 8; ++j) u[j] = xpb[(size_t)sx[j] * 64 + lane];
#pragma unroll
        for (int j = 0; j < 8; ++j) {
            float v = w[j] + ad;
            v = v > 0.f ? v : NEG_SLOPE * v;
            float p = __expf(v);
            p = (slot + j < cnt) ? p : 0.f;
            s += p;
            acc0 = fmaf(p, __uint_as_float(u[j] << 16), acc0);
            acc1 = fmaf(p, __uint_as_float(u[j] & 0xffff0000u), acc1);
        }
    }
    float inv = 1.0f / (s + SM_EPS);
    aggb[(size_t)node * 64 + lane] = bf16rne(acc0 * inv) | (bf16rne(acc1 * inv) << 16);
}

// ---------------------------------------------------------------------------
// K3: per-channel sum / sumsq of agg (bf16; bias cancels through BN).
// Thread handles channel pair cp=tid&63 at row stride; LDS reduce across the
// 4 row-groups; 256 atomics/block.
// ---------------------------------------------------------------------------
__global__ __launch_bounds__(256) void k_bnstats(
    const unsigned* __restrict__ aggb, int n, float* __restrict__ stats)
{
    __shared__ float red[4][256];   // [rowgroup][2*cp + {0:sum,1:sumsq} interleave]
    const int cp = threadIdx.x & 63;       // channel pair: c = 2cp, 2cp+1
    const int rg = threadIdx.x >> 6;       // row group 0..3
    float s0 = 0.f, s1 = 0.f, q0 = 0.f, q1 = 0.f;
    for (int r = blockIdx.x * 4 + rg; r < n; r += gridDim.x * 4) {
        unsigned u = aggb[(size_t)r * 64 + cp];
        float v0 = __uint_as_float(u << 16);
        float v1 = __uint_as_float(u & 0xffff0000u);
        s0 += v0; q0 += v0 * v0;
        s1 += v1; q1 += v1 * v1;
    }
    red[rg][cp * 2] = s0;      red[rg][cp * 2 + 1] = s1;
    red[rg][128 + cp * 2] = q0; red[rg][128 + cp * 2 + 1] = q1;
    __syncthreads();
    if (rg == 0) {
        // 64 threads fold 4 rowgroups for 4 slots each
#pragma unroll
        for (int k = 0; k < 4; ++k) {
            int idx = cp * 4 + k;   // covers 0..255
            float v = red[0][idx] + red[1][idx] + red[2][idx] + red[3][idx];
            atomicAdd(&stats[idx < 128 ? (idx >> 1) + (idx & 1) * 0 : 0] , 0.f); // placeholder avoided below
        }
    }
    __syncthreads();
    // simpler correct fold: each of first 256 threads folds its own slot
    if (threadIdx.x < 256) {
        int idx = threadIdx.x;
        float v = red[0][idx] + red[1][idx] + red[2][idx] + red[3][idx];
        // red layout: [0:128) interleaved sums (c = (idx>>1)*2 + (idx&1)),
        //             [128:256) interleaved sumsq
        int c = ((idx & 127) >> 1) * 2 + (idx & 1);
        if (idx < 128) atomicAdd(&stats[c], v);
        else           atomicAdd(&stats[128 + c], v);
    }
}

// ---------------------------------------------------------------------------
// K4: finalize: BN (batch stats of agg) + ReLU + residual. agg read as bf16.
// ---------------------------------------------------------------------------
__global__ __launch_bounds__(256) void k_final(
    const unsigned* __restrict__ aggb, const float* __restrict__ gamma,
    const float* __restrict__ beta, const float* __restrict__ stats,
    const float* __restrict__ x, float* __restrict__ out, int n)
{
    int i4 = blockIdx.x * 256 + threadIdx.x;     // index in float4 units
    int total4 = n * 32;
    if (i4 >= total4) return;
    int c4 = (i4 & 31) * 4;                      // channel base
    float invn = 1.0f / (float)n;
    uint2 au = ((const uint2*)aggb)[i4];         // 4 bf16
    float av[4] = { __uint_as_float(au.x << 16), __uint_as_float(au.x & 0xffff0000u),
                    __uint_as_float(au.y << 16), __uint_as_float(au.y & 0xffff0000u) };
    float4 xv = ((const float4*)x)[i4];
    float4 o;
#pragma unroll
    for (int j = 0; j < 4; ++j) {
        int c = c4 + j;
        float mean = stats[c] * invn;
        float var = stats[128 + c] * invn - mean * mean;
        float v = (av[j] - mean) * rsqrtf(var + BN_EPS) * gamma[c] + beta[c];
        v = fmaxf(v, 0.f);
        (&o.x)[j] = v + (&xv.x)[j];
    }
    ((float4*)out)[i4] = o;
}

// ---------------------------------------------------------------------------
extern "C" void kernel_launch(void* const* d_in, const int* in_sizes, int n_in,
                              void* d_out, int out_size, void* d_ws, size_t ws_size,
                              hipStream_t stream)
{
    const float* x        = (const float*)d_in[0];
    const int*   ei       = (const int*)d_in[1];
    const float* W        = (const float*)d_in[2];
    const float* att_src  = (const float*)d_in[3];
    const float* att_dst  = (const float*)d_in[4];
    const float* bn_gamma = (const float*)d_in[6];
    const float* bn_beta  = (const float*)d_in[7];
    float* out = (float*)d_out;

    const int n = in_sizes[0] / 128;
    const int E = in_sizes[1] / 2;

    // workspace layout: stats, deg contiguous (zeroed together in init)
    float*          stats   = (float*)d_ws;                       // 256
    int*            deg     = (int*)(stats + 256);                // n
    unsigned short* csr_src = (unsigned short*)(deg + n);         // n*SLOTS (u16)
    unsigned short* Wtg     = csr_src + (size_t)n * SLOTS;        // 144*128
    unsigned*       xpb     = (unsigned*)(Wtg + 144 * 128);       // n*64 (bf16 x2)
    unsigned*       aggb    = xpb + (size_t)n * 64;               // n*64 (bf16 x2)
    float*          a_s     = (float*)(aggb + (size_t)n * 64);    // n*8
    float*          a_d     = a_s + (size_t)n * 8;                // n*8

    const int zcount = 256 + n;
    const int ginit = 72 + (zcount + 255) / 256;
    int ggemm = 3200;                       // edge-pass TLP oversubscription
    ggemm = (ggemm + 7) & ~7;               // multiple of 8 cohorts

    k_init<<<ginit, 256, 0, stream>>>(W, att_src, att_dst, Wtg, (int*)stats, zcount);
    k_gemm<<<ggemm, 256, 0, stream>>>(x, Wtg, ei, E, xpb, a_s, a_d,
                                      deg, csr_src, n);
    k_gather<<<(n + 3) / 4, 256, 0, stream>>>(deg, csr_src, a_s, a_d, xpb, aggb, n);
    k_bnstats<<<640, 256, 0, stream>>>(aggb, n, stats);
    k_final<<<(n * 32 + 255) / 256, 256, 0, stream>>>(aggb, bn_gamma, bn_beta,
                                                      stats, x, out, n);
}

// Round 19
// 179.890 us; speedup vs baseline: 6.9011x; 6.9011x over previous
//
#include <hip/hip_runtime.h>
#include <math.h>

// GAT layer, R19: R18 with the bnstats dead-code atomics removed (R18 shipped
// a leftover placeholder loop doing 163k no-op atomicAdds on stats[0] ->
// 1079us). agg is bf16 (write once, read twice; BN normalizes so error is
// negligible). Pipeline: init -> gemm(+XCD-local edge pass) -> gather ->
// bnstats -> final.

constexpr float NEG_SLOPE = 0.2f;
constexpr float BN_EPS = 1e-5f;
constexpr float SM_EPS = 1e-16f;
constexpr int SLOTS = 96;   // fixed CSR stride per node; P(deg>=96)~1e-44

typedef __attribute__((ext_vector_type(8))) short short8;   // 8 bf16
typedef __attribute__((ext_vector_type(4))) float f32x4;    // MFMA acc

__device__ inline unsigned bf16rne(float f) {
    unsigned b = __float_as_uint(f);
    return (b + 0x7fffu + ((b >> 16) & 1u)) >> 16;
}

// ---------------------------------------------------------------------------
// K0: blocks 0..63: Wt transpose (bf16). blocks 64..71: WS/WD fused attention
// columns (a_s = x @ (W@att_src)). blocks 72..: zero stats+deg.
// ---------------------------------------------------------------------------
__global__ __launch_bounds__(256) void k_init(
    const float* __restrict__ W, const float* __restrict__ att_src,
    const float* __restrict__ att_dst, unsigned short* __restrict__ Wtg,
    int* __restrict__ zbase, int zcount)
{
    int b = blockIdx.x;
    if (b < 64) {
        int idx = b * 256 + threadIdx.x;   // 16384 total
        int k = idx >> 7, nc = idx & 127;
        Wtg[nc * 128 + k] = (unsigned short)bf16rne(W[idx]);
    } else if (b < 72) {
        int c = (b - 64) * 16 + (threadIdx.x >> 4);
        int j = threadIdx.x & 15;
        int h = j & 7;
        const float* att = (j < 8) ? att_src : att_dst;
        float v = 0.f;
#pragma unroll
        for (int f = 0; f < 16; ++f)
            v += W[c * 128 + h * 16 + f] * att[h * 16 + f];
        Wtg[(128 + j) * 128 + c] = (unsigned short)bf16rne(v);
    } else {
        int idx = (b - 72) * 256 + threadIdx.x;
        if (idx < zcount) zbase[idx] = 0;
    }
}

// ---------------------------------------------------------------------------
// K1: XCD-partitioned edge bucketing (cohort = blockIdx%8 owns dst range)
// + MFMA tiles (blocks < ntiles). ct 0..7 -> xp; ct 8 -> [a_s|a_d].
// ---------------------------------------------------------------------------
__global__ __launch_bounds__(256) void k_gemm(
    const float* __restrict__ x, const unsigned short* __restrict__ Wtg,
    const int* __restrict__ ei, int E,
    unsigned* __restrict__ xpb, float* __restrict__ a_s, float* __restrict__ a_d,
    int* __restrict__ deg, unsigned short* __restrict__ csr_src, int n)
{
    // edge pass: cohort (blockIdx%8) scans all edges, keeps dst in its range
    {
        const int xcd = blockIdx.x & 7;
        const int crank = blockIdx.x >> 3;           // rank within cohort
        const int cblocks = gridDim.x >> 3;          // blocks per cohort
        const int nodes_per = (n + 7) >> 3;
        const int dlo = xcd * nodes_per;
        const int dhi = min(n, dlo + nodes_per);
        const int tot = E + n;
        const int stride = cblocks * 256;
        for (int e = crank * 256 + threadIdx.x; e < tot; e += stride) {
            int dst = (e < E) ? ei[E + e] : (e - E);
            if (dst < dlo || dst >= dhi) continue;
            int src = (e < E) ? ei[e] : dst;
            int slot = atomicAdd(&deg[dst], 1);
            csr_src[(size_t)dst * SLOTS + slot] = (unsigned short)src;
        }
    }

    const int ntiles = (n + 63) >> 6;
    if ((int)blockIdx.x >= ntiles) return;

    const int tid = threadIdx.x;
    const int lane = tid & 63;
    const int wid = tid >> 6;
    const int quad = lane >> 4;
    const int l16 = lane & 15;
    const int row = blockIdx.x * 64 + wid * 16 + l16;

    const float4* x4 = (const float4*)x;
    short8 afrag[4];
#pragma unroll
    for (int kt = 0; kt < 4; ++kt) {
        float4 f0 = make_float4(0.f, 0.f, 0.f, 0.f), f1 = f0;
        if (row < n) {
            f0 = x4[(size_t)row * 32 + kt * 8 + quad * 2];
            f1 = x4[(size_t)row * 32 + kt * 8 + quad * 2 + 1];
        }
        short8 a;
        a[0] = (short)bf16rne(f0.x); a[1] = (short)bf16rne(f0.y);
        a[2] = (short)bf16rne(f0.z); a[3] = (short)bf16rne(f0.w);
        a[4] = (short)bf16rne(f1.x); a[5] = (short)bf16rne(f1.y);
        a[6] = (short)bf16rne(f1.z); a[7] = (short)bf16rne(f1.w);
        afrag[kt] = a;
    }

    f32x4 acc[9];
#pragma unroll
    for (int ct = 0; ct < 9; ++ct) acc[ct] = (f32x4){0.f, 0.f, 0.f, 0.f};

#pragma unroll
    for (int ct = 0; ct < 9; ++ct) {
#pragma unroll
        for (int kt = 0; kt < 4; ++kt) {
            short8 b = *(const short8*)&Wtg[(size_t)(ct * 16 + l16) * 128 + kt * 32 + quad * 8];
            acc[ct] = __builtin_amdgcn_mfma_f32_16x16x32_bf16(afrag[kt], b, acc[ct], 0, 0, 0);
        }
    }

    const int rowbase = blockIdx.x * 64 + wid * 16 + quad * 4;
#pragma unroll
    for (int ct = 0; ct < 8; ++ct) {
#pragma unroll
        for (int r = 0; r < 4; ++r) {
            float val = acc[ct][r];
            float other = __shfl_xor(val, 1);
            int orow = rowbase + r;
            if (!(lane & 1) && orow < n) {
                unsigned u = bf16rne(val) | (bf16rne(other) << 16);
                xpb[(size_t)orow * 64 + ct * 8 + (l16 >> 1)] = u;
            }
        }
    }
#pragma unroll
    for (int r = 0; r < 4; ++r) {
        int orow = rowbase + r;
        if (orow < n) {
            float val = acc[8][r];
            if (l16 < 8) a_s[(size_t)orow * 8 + l16] = val;
            else         a_d[(size_t)orow * 8 + (l16 - 8)] = val;
        }
    }
}

// ---------------------------------------------------------------------------
// K2: per-dst gather-aggregate, bf16 messages. ALL batches 8-wide (clamped
// index + zero-weighted lanes; cnt>=1 via self-loop). agg written as bf16x2.
// One wave per node, 4 nodes/block, barrier-free.
// ---------------------------------------------------------------------------
__global__ __launch_bounds__(256) void k_gather(
    const int* __restrict__ deg, const unsigned short* __restrict__ csr_src,
    const float* __restrict__ a_s, const float* __restrict__ a_d,
    const unsigned* __restrict__ xpb, unsigned* __restrict__ aggb, int n)
{
    int node = blockIdx.x * 4 + (threadIdx.x >> 6);
    if (node >= n) return;
    int lane = threadIdx.x & 63;
    int h = lane >> 3;
    float ad = a_d[(size_t)node * 8 + h];
    const unsigned short* rowp = csr_src + (size_t)node * SLOTS;
    int cnt = deg[node];
    float acc0 = 0.f, acc1 = 0.f, s = 0.f;

    for (int slot = 0; slot < cnt; slot += 8) {
        int sx[8]; float w[8]; unsigned u[8];
#pragma unroll
        for (int j = 0; j < 8; ++j) {
            int sj = slot + j;
            sx[j] = rowp[sj < cnt ? sj : cnt - 1];
        }
#pragma unroll
        for (int j = 0; j < 8; ++j) w[j] = a_s[(size_t)sx[j] * 8 + h];
#pragma unroll
        for (int j = 0; j < 8; ++j) u[j] = xpb[(size_t)sx[j] * 64 + lane];
#pragma unroll
        for (int j = 0; j < 8; ++j) {
            float v = w[j] + ad;
            v = v > 0.f ? v : NEG_SLOPE * v;
            float p = __expf(v);
            p = (slot + j < cnt) ? p : 0.f;
            s += p;
            acc0 = fmaf(p, __uint_as_float(u[j] << 16), acc0);
            acc1 = fmaf(p, __uint_as_float(u[j] & 0xffff0000u), acc1);
        }
    }
    float inv = 1.0f / (s + SM_EPS);
    aggb[(size_t)node * 64 + lane] = bf16rne(acc0 * inv) | (bf16rne(acc1 * inv) << 16);
}

// ---------------------------------------------------------------------------
// K3: per-channel sum / sumsq of agg (bf16). Thread = (channel pair, row
// group); LDS fold across row groups; 256 atomics/block.
// ---------------------------------------------------------------------------
__global__ __launch_bounds__(256) void k_bnstats(
    const unsigned* __restrict__ aggb, int n, float* __restrict__ stats)
{
    __shared__ float red[4][256];   // [rowgroup][0:128 sums | 128:256 sumsq], interleaved pairs
    const int cp = threadIdx.x & 63;       // channel pair: c = 2cp, 2cp+1
    const int rg = threadIdx.x >> 6;       // row group 0..3
    float s0 = 0.f, s1 = 0.f, q0 = 0.f, q1 = 0.f;
    for (int r = blockIdx.x * 4 + rg; r < n; r += gridDim.x * 4) {
        unsigned u = aggb[(size_t)r * 64 + cp];
        float v0 = __uint_as_float(u << 16);
        float v1 = __uint_as_float(u & 0xffff0000u);
        s0 += v0; q0 += v0 * v0;
        s1 += v1; q1 += v1 * v1;
    }
    red[rg][cp * 2] = s0;       red[rg][cp * 2 + 1] = s1;
    red[rg][128 + cp * 2] = q0; red[rg][128 + cp * 2 + 1] = q1;
    __syncthreads();
    // each of the 256 threads folds its own slot across the 4 row groups
    int idx = threadIdx.x;
    float v = red[0][idx] + red[1][idx] + red[2][idx] + red[3][idx];
    // slot idx: [0:128) sum of channel c = idx (interleave maps cp*2+b -> c), same for sumsq
    if (idx < 128) atomicAdd(&stats[idx], v);
    else           atomicAdd(&stats[128 + (idx - 128)], v);
}

// ---------------------------------------------------------------------------
// K4: finalize: BN (batch stats of agg) + ReLU + residual. agg read as bf16.
// ---------------------------------------------------------------------------
__global__ __launch_bounds__(256) void k_final(
    const unsigned* __restrict__ aggb, const float* __restrict__ gamma,
    const float* __restrict__ beta, const float* __restrict__ stats,
    const float* __restrict__ x, float* __restrict__ out, int n)
{
    int i4 = blockIdx.x * 256 + threadIdx.x;     // index in float4 units
    int total4 = n * 32;
    if (i4 >= total4) return;
    int c4 = (i4 & 31) * 4;                      // channel base
    float invn = 1.0f / (float)n;
    uint2 au = ((const uint2*)aggb)[i4];         // 4 bf16
    float av[4] = { __uint_as_float(au.x << 16), __uint_as_float(au.x & 0xffff0000u),
                    __uint_as_float(au.y << 16), __uint_as_float(au.y & 0xffff0000u) };
    float4 xv = ((const float4*)x)[i4];
    float4 o;
#pragma unroll
    for (int j = 0; j < 4; ++j) {
        int c = c4 + j;
        float mean = stats[c] * invn;
        float var = stats[128 + c] * invn - mean * mean;
        float v = (av[j] - mean) * rsqrtf(var + BN_EPS) * gamma[c] + beta[c];
        v = fmaxf(v, 0.f);
        (&o.x)[j] = v + (&xv.x)[j];
    }
    ((float4*)out)[i4] = o;
}

// ---------------------------------------------------------------------------
extern "C" void kernel_launch(void* const* d_in, const int* in_sizes, int n_in,
                              void* d_out, int out_size, void* d_ws, size_t ws_size,
                              hipStream_t stream)
{
    const float* x        = (const float*)d_in[0];
    const int*   ei       = (const int*)d_in[1];
    const float* W        = (const float*)d_in[2];
    const float* att_src  = (const float*)d_in[3];
    const float* att_dst  = (const float*)d_in[4];
    const float* bn_gamma = (const float*)d_in[6];
    const float* bn_beta  = (const float*)d_in[7];
    float* out = (float*)d_out;

    const int n = in_sizes[0] / 128;
    const int E = in_sizes[1] / 2;

    // workspace layout: stats, deg contiguous (zeroed together in init)
    float*          stats   = (float*)d_ws;                       // 256
    int*            deg     = (int*)(stats + 256);                // n
    unsigned short* csr_src = (unsigned short*)(deg + n);         // n*SLOTS (u16)
    unsigned short* Wtg     = csr_src + (size_t)n * SLOTS;        // 144*128
    unsigned*       xpb     = (unsigned*)(Wtg + 144 * 128);       // n*64 (bf16 x2)
    unsigned*       aggb    = xpb + (size_t)n * 64;               // n*64 (bf16 x2)
    float*          a_s     = (float*)(aggb + (size_t)n * 64);    // n*8
    float*          a_d     = a_s + (size_t)n * 8;                // n*8

    const int zcount = 256 + n;
    const int ginit = 72 + (zcount + 255) / 256;
    int ggemm = 3200;                       // edge-pass TLP oversubscription
    ggemm = (ggemm + 7) & ~7;               // multiple of 8 cohorts

    k_init<<<ginit, 256, 0, stream>>>(W, att_src, att_dst, Wtg, (int*)stats, zcount);
    k_gemm<<<ggemm, 256, 0, stream>>>(x, Wtg, ei, E, xpb, a_s, a_d,
                                      deg, csr_src, n);
    k_gather<<<(n + 3) / 4, 256, 0, stream>>>(deg, csr_src, a_s, a_d, xpb, aggb, n);
    k_bnstats<<<640, 256, 0, stream>>>(aggb, n, stats);
    k_final<<<(n * 32 + 255) / 256, 256, 0, stream>>>(aggb, bn_gamma, bn_beta,
                                                      stats, x, out, n);
}